// Round 5
// baseline (157.528 us; speedup 1.0000x reference)
//
// Register-chained MLP: W k-rows permuted at prep time so each layer's A-fragment
// is the previous layer's packed D in the SAME lane (zero LDS for activations).
#include <hip/hip_runtime.h>
#include <math.h>

#define RES 192
#define RANK 8
#define NI 128

typedef __attribute__((ext_vector_type(8))) _Float16 h8;
typedef __attribute__((ext_vector_type(4))) _Float16 h4;
typedef __attribute__((ext_vector_type(2))) _Float16 h2f;
typedef __attribute__((ext_vector_type(4))) float floatx4;

// packed-weight offsets in halfs (each fragment chunk: 64 lanes * 8 fp16)
#define OFF_SW0 0        // 8 ntiles * 1 kstep  * 512 = 4096
#define OFF_SW1 4096     // 8 * 4 * 512 = 16384
#define OFF_SW2 20480    // 1 * 4 * 512 = 2048
#define OFF_CW0 22528    // 4 * 1 * 512 = 2048
#define OFF_CW1 24576    // 4 * 2 * 512 = 4096
#define OFF_CW2 28672    // 1 * 2 * 512 = 1024
#define PACK_TOTAL 29696

#define TRI_CELLS (RES*RES)          // 36864 cells per plane
#define CELLS3    (3*TRI_CELLS)      // 110592
#define FG_TOTAL  (32*32*32*32)      // 1048576
#define PREP2_TOTAL (PACK_TOTAL + CELLS3 + FG_TOTAL/8)   // 271360 = 1060*256

__device__ __forceinline__ void prep_idx(float c, int size, int& i0, float& f){
    float idx = (c + 1.0f)*0.5f*(float)(size-1);
    idx = fminf(fmaxf(idx, 0.0f), (float)(size-1));
    int ii = (int)idx;               // idx >= 0, trunc == floor
    if (ii > size-2) ii = size-2;
    i0 = ii;
    f = idx - (float)ii;
}

__device__ __forceinline__ float wred64(float v){
    #pragma unroll
    for (int o=32;o>0;o>>=1) v += __shfl_down(v, o, 64);
    return v;
}

// pair exchange: xor-1 lane shuffle of an h8 (4 dword moves)
__device__ __forceinline__ h8 shx1(h8 v){
    union { h8 h; int i[4]; } u; u.h = v;
    #pragma unroll
    for (int k=0;k<4;k++) u.i[k] = __shfl_xor(u.i[k], 1, 64);
    return u.h;
}
// arbitrary-lane shuffles of h8/h4
__device__ __forceinline__ h8 shfl8(h8 v, int src){
    union { h8 h; int i[4]; } u; u.h = v;
    #pragma unroll
    for (int k=0;k<4;k++) u.i[k] = __shfl(u.i[k], src, 64);
    return u.h;
}
__device__ __forceinline__ h4 shfl4(h4 v, int src){
    union { h4 h; int i[2]; } u; u.h = v;
    #pragma unroll
    for (int k=0;k<2;k++) u.i[k] = __shfl(u.i[k], src, 64);
    return u.h;
}
__device__ __forceinline__ h8 cat44(h4 lo, h4 hi){
    return __builtin_shufflevector(lo, hi, 0,1,2,3,4,5,6,7);
}
// pack 4xf32 -> h4 with/without relu
__device__ __forceinline__ h4 pk4r(floatx4 v){
    return h4{(_Float16)fmaxf(v[0],0.f), (_Float16)fmaxf(v[1],0.f),
              (_Float16)fmaxf(v[2],0.f), (_Float16)fmaxf(v[3],0.f)};
}
__device__ __forceinline__ h4 pk4n(floatx4 v){
    return h4{(_Float16)v[0], (_Float16)v[1], (_Float16)v[2], (_Float16)v[3]};
}
__device__ __forceinline__ h8 pack8f(const float* s){
    return h8{(_Float16)s[0],(_Float16)s[1],(_Float16)s[2],(_Float16)s[3],
              (_Float16)s[4],(_Float16)s[5],(_Float16)s[6],(_Float16)s[7]};
}

// ---- fused prep (vectorized): weight packing (k-permuted) + fp16 tables ----
// k-permutation sigma(ks,q,j) = 32ks + 16*(j>>2) + 4q + (j&3) lets the fused
// kernel feed layer N+1 directly from layer N's packed D registers (same lane).
__global__ void __launch_bounds__(256) prep_all2(
    const float* __restrict__ sW0, const float* __restrict__ sW1,
    const float* __restrict__ sW2, const float* __restrict__ cW0,
    const float* __restrict__ cW1, const float* __restrict__ cW2,
    const float* __restrict__ Gxy, const float* __restrict__ Gxz,
    const float* __restrict__ Gyz, const float* __restrict__ F_grid,
    _Float16* __restrict__ Wp, _Float16* __restrict__ Gp, _Float16* __restrict__ Fg)
{
    int e = blockIdx.x*256 + threadIdx.x;
    if (e < PACK_TOTAL){
        const float* src; int K, N, ksteps, base, wt;  // wt: 0=natural 1=perm 2=cw0
        if      (e < OFF_SW1){ src=sW0; K=32;  N=128; ksteps=1; base=OFF_SW0; wt=0; }
        else if (e < OFF_SW2){ src=sW1; K=128; N=128; ksteps=4; base=OFF_SW1; wt=1; }
        else if (e < OFF_CW0){ src=sW2; K=128; N=16;  ksteps=4; base=OFF_SW2; wt=1; }
        else if (e < OFF_CW1){ src=cW0; K=31;  N=64;  ksteps=1; base=OFF_CW0; wt=2; }
        else if (e < OFF_CW2){ src=cW1; K=64;  N=64;  ksteps=2; base=OFF_CW1; wt=1; }
        else                 { src=cW2; K=64;  N=3;   ksteps=2; base=OFF_CW2; wt=1; }
        int i = e - base;
        int j = i & 7, lane = (i>>3)&63, t = i>>9;
        int ks = t % ksteps, nt = t / ksteps;
        int q = lane>>4, cn = lane&15;
        int n = nt*16 + cn;
        int ksrc;
        if (wt == 0){
            ksrc = q*8 + j;                                  // natural (L1: gather order)
        } else if (wt == 1){
            ksrc = ks*32 + 16*(j>>2) + 4*q + (j&3);          // sigma-perm (chained layers)
        } else {
            // CL1 input = [SH 0..15 | out16 0..15]; out16[0] (sigma) row zeroed.
            if (q < 2) ksrc = 8*q + j;                       // SH rows 0..15
            else { int o = 8*(q&1) + j; ksrc = (o==0) ? -1 : 15+o; }  // out16[o] -> cW0 row 15+o
        }
        float v = (ksrc >= 0 && ksrc < K && n < N) ? src[ksrc*N + n] : 0.0f;
        Wp[e] = (_Float16)v;
        return;
    }
    int e2 = e - PACK_TOTAL;
    if (e2 < CELLS3){
        // one thread per triplane cell: 24 floats -> 32 halfs (zero pad)
        int p, lc;
        if      (e2 < TRI_CELLS)   { p = 0; lc = e2; }
        else if (e2 < 2*TRI_CELLS) { p = 1; lc = e2 - TRI_CELLS; }
        else                       { p = 2; lc = e2 - 2*TRI_CELLS; }
        const float* src = ((p==0) ? Gxy : (p==1) ? Gxz : Gyz) + (size_t)lc*24;
        const float4* s4 = (const float4*)src;
        float4 a = s4[0], b = s4[1], c = s4[2], d = s4[3], ee = s4[4], ff = s4[5];
        h8 o0 = {(_Float16)a.x,(_Float16)a.y,(_Float16)a.z,(_Float16)a.w,
                 (_Float16)b.x,(_Float16)b.y,(_Float16)b.z,(_Float16)b.w};
        h8 o1 = {(_Float16)c.x,(_Float16)c.y,(_Float16)c.z,(_Float16)c.w,
                 (_Float16)d.x,(_Float16)d.y,(_Float16)d.z,(_Float16)d.w};
        h8 o2 = {(_Float16)ee.x,(_Float16)ee.y,(_Float16)ee.z,(_Float16)ee.w,
                 (_Float16)ff.x,(_Float16)ff.y,(_Float16)ff.z,(_Float16)ff.w};
        h8 zz = {0,0,0,0,0,0,0,0};
        h8* dst = (h8*)(Gp + (size_t)e2*32);
        dst[0]=o0; dst[1]=o1; dst[2]=o2; dst[3]=zz;
        return;
    }
    int t = e2 - CELLS3;   // 0..131071, 8 floats each
    const float4* s4 = (const float4*)(F_grid + (size_t)t*8);
    float4 a = s4[0], b = s4[1];
    h8 o = {(_Float16)a.x,(_Float16)a.y,(_Float16)a.z,(_Float16)a.w,
            (_Float16)b.x,(_Float16)b.y,(_Float16)b.z,(_Float16)b.w};
    ((h8*)Fg)[t] = o;
}

// --------- fused kernel: gather + register-chained MFMA MLPs + compositing ---------
// Wave wv owns samples [32wv,32wv+32). All activations stay in registers:
// layer N's packed D (h4 per nt per mtile) feeds layer N+1's A-frag via cat44
// in the SAME lane (W rows pre-permuted by prep). Cross-lane moves only at
// gather->L1 (shfl8+select) and L3->CL1 (shfl4+select). LDS = composite handoff only.
__launch_bounds__(256, 5)
__global__ void nerf_fused(
    const float* __restrict__ rays_o, const float* __restrict__ rays_d,
    const _Float16* __restrict__ Gp, const _Float16* __restrict__ Fg,
    const _Float16* __restrict__ Wp, float* __restrict__ out)
{
    __shared__ float sigmaArr[128];
    __shared__ float rgbArr[128*3];
    __shared__ float wtot[2];
    __shared__ float partial[8];

    const int tid  = threadIdx.x;
    const int lane = tid & 63;
    const int wv   = tid >> 6;           // wave 0..3
    const int ray  = blockIdx.x;

    const int rowbase = wv*32;
    const int col  = lane & 15;
    const int quad = lane >> 4;

    const float ox = rays_o[ray*3+0], oy = rays_o[ray*3+1], oz = rays_o[ray*3+2];
    const float dx = rays_d[ray*3+0], dy = rays_d[ray*3+1], dz = rays_d[ray*3+2];

    float sdx = (fabsf(dx) < 1e-9f) ? 1e-9f : dx;
    float sdy = (fabsf(dy) < 1e-9f) ? 1e-9f : dy;
    float sdz = (fabsf(dz) < 1e-9f) ? 1e-9f : dz;
    float t1x = (-1.3f - ox)/sdx, t2x = (1.3f - ox)/sdx;
    float t1y = (-1.3f - oy)/sdy, t2y = (1.3f - oy)/sdy;
    float t1z = (-1.3f - oz)/sdz, t2z = (1.3f - oz)/sdz;
    float tmin = fmaxf(fminf(t1x,t2x), fmaxf(fminf(t1y,t2y), fminf(t1z,t2z)));
    float tmax = fminf(fmaxf(t1x,t2x), fminf(fmaxf(t1y,t2y), fmaxf(t1z,t2z)));
    float nearv = fmaxf(tmin, 0.0f);

    // wave-skip: if all 32 samples of this wave are masked, outputs never read
    bool skipAll;
    {
        int sid = rowbase + (lane & 31);
        float w_ts0 = nearv + (float)sid     * 0.0352f;
        float w_ts1 = nearv + (float)(sid+1) * 0.0352f;
        float w_tm  = 0.5f*(w_ts0+w_ts1);
        float wpx = ox + w_tm*dx, wpy = oy + w_tm*dy, wpz = oz + w_tm*dz;
        bool m = (fabsf(wpx)<=1.3f) && (fabsf(wpy)<=1.3f) && (fabsf(wpz)<=1.3f)
               && (w_tm<=tmax) && (tmax>tmin);
        skipAll = (__ballot(m) == 0ULL);
    }

    if (!skipAll){
        // ---- gather: 2 lanes per sample; results stay in FVa/FVb ----
        h8 FVa = {0,0,0,0,0,0,0,0};
        h8 FVb = {0,0,0,0,0,0,0,0};
        {
            const int s = rowbase + (lane >> 1);
            const int h = lane & 1;        // zc half / F-grid ch half

            float ts0 = nearv + (float)s     * 0.0352f;
            float ts1 = nearv + (float)(s+1) * 0.0352f;
            float tmid = 0.5f*(ts0+ts1);
            float px = ox + tmid*dx, py = oy + tmid*dy, pz = oz + tmid*dz;
            bool mask = (fabsf(px)<=1.3f) && (fabsf(py)<=1.3f) && (fabsf(pz)<=1.3f)
                      && (tmid<=tmax) && (tmax>tmin);

            if (mask){
                float p0 = (px/1.3f + 1.0f)*192.0f/2.0f*2.0f/192.0f - 1.0f;
                float p1 = (py/1.3f + 1.0f)*192.0f/2.0f*2.0f/192.0f - 1.0f;
                float p2 = (pz/1.3f + 1.0f)*192.0f/2.0f*2.0f/192.0f - 1.0f;

                int x0, y0, z0; float fx, fy, fz;
                prep_idx(p0, RES, x0, fx);
                prep_idx(p1, RES, y0, fy);
                prep_idx(p2, RES, z0, fz);

                const int zi  = z0 + h;
                const float wzc = h ? fz : (1.0f - fz);
                const int yiA = y0 + h;        // yc = h    (yo=0)
                const int yiB = y0 + 1 - h;    // yc = 1-h  (yo=1)

                h8 XYA[3], XYB[3], XZ0[3], XZ1[3], YZo0[3], YZo1[3];
                {
                    const int oxyA = (zi*RES + yiA)*32;
                    const int oxyB = (zi*RES + yiB)*32;
                    const int ox0  = (TRI_CELLS + zi*RES + x0)*32;
                    const int oy0  = (2*TRI_CELLS + yiA*RES + x0)*32;
                    const h8* pxyA = (const h8*)(Gp + oxyA);
                    const h8* pxyB = (const h8*)(Gp + oxyB);
                    const h8* px0  = (const h8*)(Gp + ox0);
                    const h8* px1  = (const h8*)(Gp + ox0 + 32);
                    const h8* py0  = (const h8*)(Gp + oy0);
                    const h8* py1  = (const h8*)(Gp + oy0 + 32);
                    #pragma unroll
                    for (int q2=0;q2<3;q2++){
                        XYA[q2]=pxyA[q2]; XYB[q2]=pxyB[q2];
                        XZ0[q2]=px0[q2];  XZ1[q2]=px1[q2];
                        YZo0[q2]=py0[q2]; YZo1[q2]=py1[q2];
                    }
                }
                // partner's YZ row (yc = 1-h); pair lanes have identical mask
                h8 YZp0[3], YZp1[3];
                #pragma unroll
                for (int q2=0;q2<3;q2++){ YZp0[q2]=shx1(YZo0[q2]); YZp1[q2]=shx1(YZo1[q2]); }

                const float wyA = h ? fy : (1.0f - fy);
                const float wyB = h ? (1.0f - fy) : fy;

                h8 ACC0 = {0,0,0,0,0,0,0,0};
                h8 ACC1 = {0,0,0,0,0,0,0,0};
                h8 ACC2 = {0,0,0,0,0,0,0,0};
                #pragma unroll
                for (int yo=0; yo<2; yo++){
                    const float wy = yo ? wyB : wyA;
                    #pragma unroll
                    for (int xc=0; xc<2; xc++){
                        const float wx = xc ? fx : (1.0f - fx);
                        const _Float16 wh = (_Float16)(wzc*wy*wx);
                        const h8 w8 = {wh,wh,wh,wh,wh,wh,wh,wh};
                        h8 Q0, Q1, Q2;
                        if (yo==0){
                            const h8* YZv = xc ? YZo1 : YZo0;
                            Q0 = (XYA[0]*(xc?XZ1[0]:XZ0[0]))*YZv[0];
                            Q1 = (XYA[1]*(xc?XZ1[1]:XZ0[1]))*YZv[1];
                            Q2 = (XYA[2]*(xc?XZ1[2]:XZ0[2]))*YZv[2];
                        } else {
                            const h8* YZv = xc ? YZp1 : YZp0;
                            Q0 = (XYB[0]*(xc?XZ1[0]:XZ0[0]))*YZv[0];
                            Q1 = (XYB[1]*(xc?XZ1[1]:XZ0[1]))*YZv[1];
                            Q2 = (XYB[2]*(xc?XZ1[2]:XZ0[2]))*YZv[2];
                        }
                        ACC0 = __builtin_elementwise_fma(Q0, w8, ACC0);
                        ACC1 = __builtin_elementwise_fma(Q1, w8, ACC1);
                        ACC2 = __builtin_elementwise_fma(Q2, w8, ACC2);
                    }
                }
                // horizontal sums 8 -> 1
                h2f a0h = __builtin_shufflevector(ACC0,ACC0,0,1) + __builtin_shufflevector(ACC0,ACC0,2,3);
                h2f b0h = __builtin_shufflevector(ACC0,ACC0,4,5) + __builtin_shufflevector(ACC0,ACC0,6,7);
                h2f c0h = a0h + b0h;
                float gv0 = (float)c0h[0] + (float)c0h[1];
                h2f a1h = __builtin_shufflevector(ACC1,ACC1,0,1) + __builtin_shufflevector(ACC1,ACC1,2,3);
                h2f b1h = __builtin_shufflevector(ACC1,ACC1,4,5) + __builtin_shufflevector(ACC1,ACC1,6,7);
                h2f c1h = a1h + b1h;
                float gv1 = (float)c1h[0] + (float)c1h[1];
                h2f a2h = __builtin_shufflevector(ACC2,ACC2,0,1) + __builtin_shufflevector(ACC2,ACC2,2,3);
                h2f b2h = __builtin_shufflevector(ACC2,ACC2,4,5) + __builtin_shufflevector(ACC2,ACC2,6,7);
                h2f c2h = a2h + b2h;
                float gv2 = (float)c2h[0] + (float)c2h[1];

                // combine the two zc halves
                gv0 += __shfl_xor(gv0, 1, 64);
                gv1 += __shfl_xor(gv1, 1, 64);
                gv2 += __shfl_xor(gv2, 1, 64);

                // F-grid: channels [16h,16h+16) of all 8 corners
                int a0,b0,c0; float fa,fb,fc;
                prep_idx(gv2, 32, a0, fa);
                prep_idx(gv1, 32, b0, fb);
                prep_idx(gv0, 32, c0, fc);
                #pragma unroll
                for (int zc=0; zc<2; zc++){
                    const int zi2 = a0+zc; const float wz2 = zc ? fa : 1.f-fa;
                    #pragma unroll
                    for (int yc=0; yc<2; yc++){
                        const int yi2 = b0+yc; const float wy2 = yc ? fb : 1.f-fb;
                        #pragma unroll
                        for (int xc=0; xc<2; xc++){
                            const int xi2 = c0+xc; const float wx2 = xc ? fc : 1.f-fc;
                            const _Float16 wh = (_Float16)(wz2*wy2*wx2);
                            const h8 w8 = {wh,wh,wh,wh,wh,wh,wh,wh};
                            const int fo = ((zi2*32+yi2)*32+xi2)*32 + h*16;
                            const h8* pf = (const h8*)(Fg + fo);
                            FVa = __builtin_elementwise_fma(pf[0], w8, FVa);
                            FVb = __builtin_elementwise_fma(pf[1], w8, FVb);
                        }
                    }
                }
            }
        }
        // FVa = feats[16h..16h+7], FVb = feats[16h+8..16h+15] of sample rowbase+(lane>>1)

        // ---- L1 A-frags: sample col's feats 8q..8q+7 live in lane 2*col+(q>>1) ----
        h8 A1f[2];
        #pragma unroll
        for (int m=0; m<2; m++){
            int srcl = 32*m + 2*col + (quad>>1);
            h8 va = shfl8(FVa, srcl);
            h8 vb = shfl8(FVb, srcl);
            A1f[m] = (quad & 1) ? vb : va;
        }

        // L1: 32 -> 128, relu, packed D in regs
        h4 pk1[2][8];
        {
            const h8* W = (const h8*)(Wp + OFF_SW0);
            #pragma unroll
            for (int nt=0; nt<8; nt++){
                h8 b = W[nt*64 + lane];
                floatx4 c0v = {0.f,0.f,0.f,0.f}, c1v = {0.f,0.f,0.f,0.f};
                c0v = __builtin_amdgcn_mfma_f32_16x16x32_f16(b, A1f[0], c0v, 0,0,0);
                c1v = __builtin_amdgcn_mfma_f32_16x16x32_f16(b, A1f[1], c1v, 0,0,0);
                pk1[0][nt] = pk4r(c0v);
                pk1[1][nt] = pk4r(c1v);
            }
        }

        // L2: 128 -> 128, relu (A-frag = cat of own pk1 pair; W pre-permuted)
        h4 pk2[2][8];
        {
            const h8* W = (const h8*)(Wp + OFF_SW1);
            #pragma unroll
            for (int nt=0; nt<8; nt++){
                floatx4 c0v = {0.f,0.f,0.f,0.f}, c1v = {0.f,0.f,0.f,0.f};
                #pragma unroll
                for (int ks=0; ks<4; ks++){
                    h8 b  = W[(nt*4+ks)*64 + lane];
                    h8 a0 = cat44(pk1[0][2*ks], pk1[0][2*ks+1]);
                    h8 a1 = cat44(pk1[1][2*ks], pk1[1][2*ks+1]);
                    c0v = __builtin_amdgcn_mfma_f32_16x16x32_f16(b, a0, c0v, 0,0,0);
                    c1v = __builtin_amdgcn_mfma_f32_16x16x32_f16(b, a1, c1v, 0,0,0);
                }
                pk2[0][nt] = pk4r(c0v);
                pk2[1][nt] = pk4r(c1v);
            }
        }

        // L3: 128 -> 16 (no relu); sigma -> LDS; out16 + SH -> CL1 A-frags
        h8 AC1[2];
        {
            const h8* W = (const h8*)(Wp + OFF_SW2);
            floatx4 d0 = {0.f,0.f,0.f,0.f}, d1 = {0.f,0.f,0.f,0.f};
            #pragma unroll
            for (int ks=0; ks<4; ks++){
                h8 b  = W[ks*64 + lane];
                h8 a0 = cat44(pk2[0][2*ks], pk2[0][2*ks+1]);
                h8 a1 = cat44(pk2[1][2*ks], pk2[1][2*ks+1]);
                d0 = __builtin_amdgcn_mfma_f32_16x16x32_f16(b, a0, d0, 0,0,0);
                d1 = __builtin_amdgcn_mfma_f32_16x16x32_f16(b, a1, d1, 0,0,0);
            }
            if (quad == 0){
                sigmaArr[rowbase + col]      = d0[0];
                sigmaArr[rowbase + 16 + col] = d1[0];
            }
            h4 pk3_0 = pk4n(d0), pk3_1 = pk4n(d1);   // out16[4q..4q+3] per lane

            // SH basis (ray-uniform), register-resident
            const float dn = sqrtf(dx*dx+dy*dy+dz*dz);
            const float X = dx/dn, Y = dy/dn, Z = dz/dn;
            const float X2=X*X, Y2=Y*Y, Z2=Z*Z;
            float sh[16];
            sh[0]= 0.28209479177387814f;
            sh[1]=-0.48860251190291987f*Y;
            sh[2]= 0.48860251190291987f*Z;
            sh[3]=-0.48860251190291987f*X;
            sh[4]= 1.0925484305920792f*X*Y;
            sh[5]=-1.0925484305920792f*Y*Z;
            sh[6]= 0.94617469575756f*Z2 - 0.31539156525252f;
            sh[7]=-1.0925484305920792f*X*Z;
            sh[8]= 0.5462742152960396f*(X2-Y2);
            sh[9]= 0.5900435899266435f*Y*(-3.0f*X2+Y2);
            sh[10]=2.890611442640554f*X*Y*Z;
            sh[11]=0.4570457994644657f*Y*(1.0f-5.0f*Z2);
            sh[12]=0.3731763325901154f*Z*(5.0f*Z2-3.0f);
            sh[13]=0.4570457994644657f*X*(1.0f-5.0f*Z2);
            sh[14]=1.445305721320277f*Z*(X2-Y2);
            sh[15]=0.5900435899266435f*X*(-X2+3.0f*Y2);
            h8 shlo = pack8f(sh);
            h8 shhi = pack8f(sh+8);
            h8 Ash  = (quad & 1) ? shhi : shlo;

            // CL1 slots: quad 0,1 = SH[8q..8q+7]; quad 2,3 = out16[8(q&1)..+7]
            // out16[o] lives at lane (o>>2)*16+col, elem o&3.
            int ilo = (quad & 1)*32 + col;
            h4 lo0 = shfl4(pk3_0, ilo), hi0 = shfl4(pk3_0, ilo+16);
            h4 lo1 = shfl4(pk3_1, ilo), hi1 = shfl4(pk3_1, ilo+16);
            AC1[0] = (quad < 2) ? Ash : cat44(lo0, hi0);
            AC1[1] = (quad < 2) ? Ash : cat44(lo1, hi1);
        }

        // CL1: 32 -> 64, relu
        h4 pkc1[2][4];
        {
            const h8* W = (const h8*)(Wp + OFF_CW0);
            #pragma unroll
            for (int nt=0; nt<4; nt++){
                h8 b = W[nt*64 + lane];
                floatx4 c0v = {0.f,0.f,0.f,0.f}, c1v = {0.f,0.f,0.f,0.f};
                c0v = __builtin_amdgcn_mfma_f32_16x16x32_f16(b, AC1[0], c0v, 0,0,0);
                c1v = __builtin_amdgcn_mfma_f32_16x16x32_f16(b, AC1[1], c1v, 0,0,0);
                pkc1[0][nt] = pk4r(c0v);
                pkc1[1][nt] = pk4r(c1v);
            }
        }

        // CL2: 64 -> 64, relu
        h4 pkc2[2][4];
        {
            const h8* W = (const h8*)(Wp + OFF_CW1);
            #pragma unroll
            for (int nt=0; nt<4; nt++){
                floatx4 c0v = {0.f,0.f,0.f,0.f}, c1v = {0.f,0.f,0.f,0.f};
                #pragma unroll
                for (int ks=0; ks<2; ks++){
                    h8 b  = W[(nt*2+ks)*64 + lane];
                    h8 a0 = cat44(pkc1[0][2*ks], pkc1[0][2*ks+1]);
                    h8 a1 = cat44(pkc1[1][2*ks], pkc1[1][2*ks+1]);
                    c0v = __builtin_amdgcn_mfma_f32_16x16x32_f16(b, a0, c0v, 0,0,0);
                    c1v = __builtin_amdgcn_mfma_f32_16x16x32_f16(b, a1, c1v, 0,0,0);
                }
                pkc2[0][nt] = pk4r(c0v);
                pkc2[1][nt] = pk4r(c1v);
            }
        }

        // CL3: 64 -> 3, no relu -> rgbArr (quad 0 holds channels 0..3)
        {
            const h8* W = (const h8*)(Wp + OFF_CW2);
            floatx4 d0 = {0.f,0.f,0.f,0.f}, d1 = {0.f,0.f,0.f,0.f};
            #pragma unroll
            for (int ks=0; ks<2; ks++){
                h8 b  = W[ks*64 + lane];
                h8 a0 = cat44(pkc2[0][2*ks], pkc2[0][2*ks+1]);
                h8 a1 = cat44(pkc2[1][2*ks], pkc2[1][2*ks+1]);
                d0 = __builtin_amdgcn_mfma_f32_16x16x32_f16(b, a0, d0, 0,0,0);
                d1 = __builtin_amdgcn_mfma_f32_16x16x32_f16(b, a1, d1, 0,0,0);
            }
            if (quad == 0){
                #pragma unroll
                for (int r=0;r<3;r++){
                    rgbArr[(rowbase + col)*3 + r]      = d0[r];
                    rgbArr[(rowbase + 16 + col)*3 + r] = d1[r];
                }
            }
        }
    }

    __syncthreads();   // cross-wave handoff: sigmaArr/rgbArr -> waves 0,1

    // ---------------- compositing (threads 0..127, sample = tid) ----------------
    {
        float alpha = 0.f, rr = 0.f, rg = 0.f, rb = 0.f;
        if (tid < 128){
            float ts0 = nearv + (float)tid     * 0.0352f;
            float ts1 = nearv + (float)(tid+1) * 0.0352f;
            float tmid = 0.5f*(ts0+ts1);
            float dist = ts1 - ts0;
            float px = ox + tmid*dx, py = oy + tmid*dy, pz = oz + tmid*dz;
            bool mask = (fabsf(px)<=1.3f) && (fabsf(py)<=1.3f) && (fabsf(pz)<=1.3f)
                      && (tmid<=tmax) && (tmax>tmin);
            float sg = mask ? fmaxf(sigmaArr[tid], 0.f) : 0.f;
            alpha = 1.0f - expf(-sg*dist);
            if (mask){
                rr = 1.0f/(1.0f+expf(-rgbArr[tid*3+0]));
                rg = 1.0f/(1.0f+expf(-rgbArr[tid*3+1]));
                rb = 1.0f/(1.0f+expf(-rgbArr[tid*3+2]));
            }
        }
        float p = 1.0f - alpha + 1e-10f;
        #pragma unroll
        for (int off=1; off<64; off<<=1){
            float u = __shfl_up(p, off, 64);
            if (lane >= off) p *= u;
        }
        if (tid < 128 && lane == 63) wtot[wv] = p;
        float excl = __shfl_up(p, 1, 64);
        if (lane == 0) excl = 1.0f;
        __syncthreads();
        if (tid < 128){
            float T = excl;
            if (wv == 1) T *= wtot[0];
            float w = alpha * T;
            float v0 = wred64(w*rr);
            float v1 = wred64(w*rg);
            float v2 = wred64(w*rb);
            float v3 = wred64(w);
            if (lane == 0){
                partial[wv*4+0]=v0; partial[wv*4+1]=v1; partial[wv*4+2]=v2; partial[wv*4+3]=v3;
            }
        }
        __syncthreads();
        if (tid == 0){
            float acc = partial[3] + partial[7];
            float bg  = 1.0f - acc;
            out[ray*3+0] = partial[0] + partial[4] + bg;
            out[ray*3+1] = partial[1] + partial[5] + bg;
            out[ray*3+2] = partial[2] + partial[6] + bg;
        }
    }
}

extern "C" void kernel_launch(void* const* d_in, const int* in_sizes, int n_in,
                              void* d_out, int out_size, void* d_ws, size_t ws_size,
                              hipStream_t stream){
    const float* rays_o = (const float*)d_in[0];
    const float* rays_d = (const float*)d_in[1];
    const float* Gxy    = (const float*)d_in[2];
    const float* Gxz    = (const float*)d_in[3];
    const float* Gyz    = (const float*)d_in[4];
    const float* F_grid = (const float*)d_in[5];
    const float* sW0    = (const float*)d_in[6];
    const float* sW1    = (const float*)d_in[7];
    const float* sW2    = (const float*)d_in[8];
    const float* cW0    = (const float*)d_in[9];
    const float* cW1    = (const float*)d_in[10];
    const float* cW2    = (const float*)d_in[11];

    _Float16* Wp = (_Float16*)d_ws;                     // packed weights (59.4 KB)
    _Float16* Gp = Wp + PACK_TOTAL;                     // padded fp16 triplanes, 7.08 MB
    _Float16* Fg = Gp + (size_t)3*TRI_CELLS*32;         // fp16 F_grid, 2.1 MB

    prep_all2<<<PREP2_TOTAL/256, 256, 0, stream>>>(sW0,sW1,sW2,cW0,cW1,cW2,
                                                   Gxy,Gxz,Gyz,F_grid, Wp,Gp,Fg);
    nerf_fused<<<2048, 256, 0, stream>>>(rays_o, rays_d, Gp, Fg, Wp, (float*)d_out);
}

// Round 6
// 132.876 us; speedup vs baseline: 1.1855x; 1.1855x over previous
//
// Register-chained MLP (round-5 math, verified) + spill fix:
// per-q gather loop with early horizontal sums (peak ~50 VGPR in gather) and
// __launch_bounds__(256,4) (128-VGPR cap, no scratch).
#include <hip/hip_runtime.h>
#include <math.h>

#define RES 192
#define RANK 8
#define NI 128

typedef __attribute__((ext_vector_type(8))) _Float16 h8;
typedef __attribute__((ext_vector_type(4))) _Float16 h4;
typedef __attribute__((ext_vector_type(2))) _Float16 h2f;
typedef __attribute__((ext_vector_type(4))) float floatx4;

// packed-weight offsets in halfs (each fragment chunk: 64 lanes * 8 fp16)
#define OFF_SW0 0        // 8 ntiles * 1 kstep  * 512 = 4096
#define OFF_SW1 4096     // 8 * 4 * 512 = 16384
#define OFF_SW2 20480    // 1 * 4 * 512 = 2048
#define OFF_CW0 22528    // 4 * 1 * 512 = 2048
#define OFF_CW1 24576    // 4 * 2 * 512 = 4096
#define OFF_CW2 28672    // 1 * 2 * 512 = 1024
#define PACK_TOTAL 29696

#define TRI_CELLS (RES*RES)          // 36864 cells per plane
#define CELLS3    (3*TRI_CELLS)      // 110592
#define FG_TOTAL  (32*32*32*32)      // 1048576
#define PREP2_TOTAL (PACK_TOTAL + CELLS3 + FG_TOTAL/8)   // 271360 = 1060*256

__device__ __forceinline__ void prep_idx(float c, int size, int& i0, float& f){
    float idx = (c + 1.0f)*0.5f*(float)(size-1);
    idx = fminf(fmaxf(idx, 0.0f), (float)(size-1));
    int ii = (int)idx;               // idx >= 0, trunc == floor
    if (ii > size-2) ii = size-2;
    i0 = ii;
    f = idx - (float)ii;
}

__device__ __forceinline__ float wred64(float v){
    #pragma unroll
    for (int o=32;o>0;o>>=1) v += __shfl_down(v, o, 64);
    return v;
}

// pair exchange: xor-1 lane shuffle of an h8 (4 dword moves)
__device__ __forceinline__ h8 shx1(h8 v){
    union { h8 h; int i[4]; } u; u.h = v;
    #pragma unroll
    for (int k=0;k<4;k++) u.i[k] = __shfl_xor(u.i[k], 1, 64);
    return u.h;
}
// arbitrary-lane shuffles of h8/h4
__device__ __forceinline__ h8 shfl8(h8 v, int src){
    union { h8 h; int i[4]; } u; u.h = v;
    #pragma unroll
    for (int k=0;k<4;k++) u.i[k] = __shfl(u.i[k], src, 64);
    return u.h;
}
__device__ __forceinline__ h4 shfl4(h4 v, int src){
    union { h4 h; int i[2]; } u; u.h = v;
    #pragma unroll
    for (int k=0;k<2;k++) u.i[k] = __shfl(u.i[k], src, 64);
    return u.h;
}
__device__ __forceinline__ h8 cat44(h4 lo, h4 hi){
    return __builtin_shufflevector(lo, hi, 0,1,2,3,4,5,6,7);
}
// pack 4xf32 -> h4 with/without relu
__device__ __forceinline__ h4 pk4r(floatx4 v){
    return h4{(_Float16)fmaxf(v[0],0.f), (_Float16)fmaxf(v[1],0.f),
              (_Float16)fmaxf(v[2],0.f), (_Float16)fmaxf(v[3],0.f)};
}
__device__ __forceinline__ h4 pk4n(floatx4 v){
    return h4{(_Float16)v[0], (_Float16)v[1], (_Float16)v[2], (_Float16)v[3]};
}
__device__ __forceinline__ h8 pack8f(const float* s){
    return h8{(_Float16)s[0],(_Float16)s[1],(_Float16)s[2],(_Float16)s[3],
              (_Float16)s[4],(_Float16)s[5],(_Float16)s[6],(_Float16)s[7]};
}

// ---- fused prep (vectorized): weight packing (k-permuted) + fp16 tables ----
// k-permutation sigma(ks,q,j) = 32ks + 16*(j>>2) + 4q + (j&3) lets the fused
// kernel feed layer N+1 directly from layer N's packed D registers (same lane).
__global__ void __launch_bounds__(256) prep_all2(
    const float* __restrict__ sW0, const float* __restrict__ sW1,
    const float* __restrict__ sW2, const float* __restrict__ cW0,
    const float* __restrict__ cW1, const float* __restrict__ cW2,
    const float* __restrict__ Gxy, const float* __restrict__ Gxz,
    const float* __restrict__ Gyz, const float* __restrict__ F_grid,
    _Float16* __restrict__ Wp, _Float16* __restrict__ Gp, _Float16* __restrict__ Fg)
{
    int e = blockIdx.x*256 + threadIdx.x;
    if (e < PACK_TOTAL){
        const float* src; int K, N, ksteps, base, wt;  // wt: 0=natural 1=perm 2=cw0
        if      (e < OFF_SW1){ src=sW0; K=32;  N=128; ksteps=1; base=OFF_SW0; wt=0; }
        else if (e < OFF_SW2){ src=sW1; K=128; N=128; ksteps=4; base=OFF_SW1; wt=1; }
        else if (e < OFF_CW0){ src=sW2; K=128; N=16;  ksteps=4; base=OFF_SW2; wt=1; }
        else if (e < OFF_CW1){ src=cW0; K=31;  N=64;  ksteps=1; base=OFF_CW0; wt=2; }
        else if (e < OFF_CW2){ src=cW1; K=64;  N=64;  ksteps=2; base=OFF_CW1; wt=1; }
        else                 { src=cW2; K=64;  N=3;   ksteps=2; base=OFF_CW2; wt=1; }
        int i = e - base;
        int j = i & 7, lane = (i>>3)&63, t = i>>9;
        int ks = t % ksteps, nt = t / ksteps;
        int q = lane>>4, cn = lane&15;
        int n = nt*16 + cn;
        int ksrc;
        if (wt == 0){
            ksrc = q*8 + j;                                  // natural (L1: gather order)
        } else if (wt == 1){
            ksrc = ks*32 + 16*(j>>2) + 4*q + (j&3);          // sigma-perm (chained layers)
        } else {
            // CL1 input = [SH 0..15 | out16 0..15]; out16[0] (sigma) row zeroed.
            if (q < 2) ksrc = 8*q + j;                       // SH rows 0..15
            else { int o = 8*(q&1) + j; ksrc = (o==0) ? -1 : 15+o; }  // out16[o] -> cW0 row 15+o
        }
        float v = (ksrc >= 0 && ksrc < K && n < N) ? src[ksrc*N + n] : 0.0f;
        Wp[e] = (_Float16)v;
        return;
    }
    int e2 = e - PACK_TOTAL;
    if (e2 < CELLS3){
        // one thread per triplane cell: 24 floats -> 32 halfs (zero pad)
        int p, lc;
        if      (e2 < TRI_CELLS)   { p = 0; lc = e2; }
        else if (e2 < 2*TRI_CELLS) { p = 1; lc = e2 - TRI_CELLS; }
        else                       { p = 2; lc = e2 - 2*TRI_CELLS; }
        const float* src = ((p==0) ? Gxy : (p==1) ? Gxz : Gyz) + (size_t)lc*24;
        const float4* s4 = (const float4*)src;
        float4 a = s4[0], b = s4[1], c = s4[2], d = s4[3], ee = s4[4], ff = s4[5];
        h8 o0 = {(_Float16)a.x,(_Float16)a.y,(_Float16)a.z,(_Float16)a.w,
                 (_Float16)b.x,(_Float16)b.y,(_Float16)b.z,(_Float16)b.w};
        h8 o1 = {(_Float16)c.x,(_Float16)c.y,(_Float16)c.z,(_Float16)c.w,
                 (_Float16)d.x,(_Float16)d.y,(_Float16)d.z,(_Float16)d.w};
        h8 o2 = {(_Float16)ee.x,(_Float16)ee.y,(_Float16)ee.z,(_Float16)ee.w,
                 (_Float16)ff.x,(_Float16)ff.y,(_Float16)ff.z,(_Float16)ff.w};
        h8 zz = {0,0,0,0,0,0,0,0};
        h8* dst = (h8*)(Gp + (size_t)e2*32);
        dst[0]=o0; dst[1]=o1; dst[2]=o2; dst[3]=zz;
        return;
    }
    int t = e2 - CELLS3;   // 0..131071, 8 floats each
    const float4* s4 = (const float4*)(F_grid + (size_t)t*8);
    float4 a = s4[0], b = s4[1];
    h8 o = {(_Float16)a.x,(_Float16)a.y,(_Float16)a.z,(_Float16)a.w,
            (_Float16)b.x,(_Float16)b.y,(_Float16)b.z,(_Float16)b.w};
    ((h8*)Fg)[t] = o;
}

// --------- fused kernel: gather + register-chained MFMA MLPs + compositing ---------
// Wave wv owns samples [32wv,32wv+32). All activations stay in registers:
// layer N's packed D (h4 per nt per mtile) feeds layer N+1's A-frag via cat44
// in the SAME lane (W rows pre-permuted by prep). Cross-lane moves only at
// gather->L1 (shfl8+select) and L3->CL1 (shfl4+select). LDS = composite handoff only.
// Gather runs as a per-channel (q) loop with early horizontal sums to keep the
// peak live set under the 128-VGPR cap (launch_bounds 256,4) -> no scratch.
__launch_bounds__(256, 4)
__global__ void nerf_fused(
    const float* __restrict__ rays_o, const float* __restrict__ rays_d,
    const _Float16* __restrict__ Gp, const _Float16* __restrict__ Fg,
    const _Float16* __restrict__ Wp, float* __restrict__ out)
{
    __shared__ float sigmaArr[128];
    __shared__ float rgbArr[128*3];
    __shared__ float wtot[2];
    __shared__ float partial[8];

    const int tid  = threadIdx.x;
    const int lane = tid & 63;
    const int wv   = tid >> 6;           // wave 0..3
    const int ray  = blockIdx.x;

    const int rowbase = wv*32;
    const int col  = lane & 15;
    const int quad = lane >> 4;

    const float ox = rays_o[ray*3+0], oy = rays_o[ray*3+1], oz = rays_o[ray*3+2];
    const float dx = rays_d[ray*3+0], dy = rays_d[ray*3+1], dz = rays_d[ray*3+2];

    float sdx = (fabsf(dx) < 1e-9f) ? 1e-9f : dx;
    float sdy = (fabsf(dy) < 1e-9f) ? 1e-9f : dy;
    float sdz = (fabsf(dz) < 1e-9f) ? 1e-9f : dz;
    float t1x = (-1.3f - ox)/sdx, t2x = (1.3f - ox)/sdx;
    float t1y = (-1.3f - oy)/sdy, t2y = (1.3f - oy)/sdy;
    float t1z = (-1.3f - oz)/sdz, t2z = (1.3f - oz)/sdz;
    float tmin = fmaxf(fminf(t1x,t2x), fmaxf(fminf(t1y,t2y), fminf(t1z,t2z)));
    float tmax = fminf(fmaxf(t1x,t2x), fminf(fmaxf(t1y,t2y), fmaxf(t1z,t2z)));
    float nearv = fmaxf(tmin, 0.0f);

    // wave-skip: if all 32 samples of this wave are masked, outputs never read
    bool skipAll;
    {
        int sid = rowbase + (lane & 31);
        float w_ts0 = nearv + (float)sid     * 0.0352f;
        float w_ts1 = nearv + (float)(sid+1) * 0.0352f;
        float w_tm  = 0.5f*(w_ts0+w_ts1);
        float wpx = ox + w_tm*dx, wpy = oy + w_tm*dy, wpz = oz + w_tm*dz;
        bool m = (fabsf(wpx)<=1.3f) && (fabsf(wpy)<=1.3f) && (fabsf(wpz)<=1.3f)
               && (w_tm<=tmax) && (tmax>tmin);
        skipAll = (__ballot(m) == 0ULL);
    }

    if (!skipAll){
        // ---- gather: 2 lanes per sample; results stay in FVa/FVb ----
        h8 FVa = {0,0,0,0,0,0,0,0};
        h8 FVb = {0,0,0,0,0,0,0,0};
        {
            const int s = rowbase + (lane >> 1);
            const int h = lane & 1;        // zc half / F-grid ch half

            float ts0 = nearv + (float)s     * 0.0352f;
            float ts1 = nearv + (float)(s+1) * 0.0352f;
            float tmid = 0.5f*(ts0+ts1);
            float px = ox + tmid*dx, py = oy + tmid*dy, pz = oz + tmid*dz;
            bool mask = (fabsf(px)<=1.3f) && (fabsf(py)<=1.3f) && (fabsf(pz)<=1.3f)
                      && (tmid<=tmax) && (tmax>tmin);

            if (mask){
                float p0 = (px/1.3f + 1.0f)*192.0f/2.0f*2.0f/192.0f - 1.0f;
                float p1 = (py/1.3f + 1.0f)*192.0f/2.0f*2.0f/192.0f - 1.0f;
                float p2 = (pz/1.3f + 1.0f)*192.0f/2.0f*2.0f/192.0f - 1.0f;

                int x0, y0, z0; float fx, fy, fz;
                prep_idx(p0, RES, x0, fx);
                prep_idx(p1, RES, y0, fy);
                prep_idx(p2, RES, z0, fz);

                const int zi  = z0 + h;
                const float wzc = h ? fz : (1.0f - fz);
                const int yiA = y0 + h;        // yc = h    (yo=0)
                const int yiB = y0 + 1 - h;    // yc = 1-h  (yo=1)
                const float wyA = h ? fy : (1.0f - fy);
                const float wyB = h ? (1.0f - fy) : fy;

                // 4 trilinear weights (zc folded), order (yo,xc) = 00,01,10,11
                const _Float16 w00 = (_Float16)(wzc*wyA*(1.0f-fx));
                const _Float16 w01 = (_Float16)(wzc*wyA*fx);
                const _Float16 w10 = (_Float16)(wzc*wyB*(1.0f-fx));
                const _Float16 w11 = (_Float16)(wzc*wyB*fx);

                const int oxyA = (zi*RES + yiA)*32;
                const int oxyB = (zi*RES + yiB)*32;
                const int ox0  = (TRI_CELLS + zi*RES + x0)*32;
                const int oy0  = (2*TRI_CELLS + yiA*RES + x0)*32;
                const h8* pxyA = (const h8*)(Gp + oxyA);
                const h8* pxyB = (const h8*)(Gp + oxyB);
                const h8* px0  = (const h8*)(Gp + ox0);
                const h8* px1  = (const h8*)(Gp + ox0 + 32);
                const h8* py0  = (const h8*)(Gp + oy0);
                const h8* py1  = (const h8*)(Gp + oy0 + 32);

                // per-channel loop: 6 loads + 2 pair-shuffles + 4 fma + hsum, then dead
                float gv[3];
                #pragma unroll
                for (int q2=0; q2<3; q2++){
                    h8 XYa = pxyA[q2], XYb = pxyB[q2];
                    h8 Xz0 = px0[q2],  Xz1 = px1[q2];
                    h8 Yo0 = py0[q2],  Yo1 = py1[q2];
                    h8 Yp0 = shx1(Yo0), Yp1 = shx1(Yo1);
                    h8 ACC = {0,0,0,0,0,0,0,0};
                    {
                        const h8 w8 = {w00,w00,w00,w00,w00,w00,w00,w00};
                        ACC = __builtin_elementwise_fma((XYa*Xz0)*Yo0, w8, ACC);
                    }
                    {
                        const h8 w8 = {w01,w01,w01,w01,w01,w01,w01,w01};
                        ACC = __builtin_elementwise_fma((XYa*Xz1)*Yo1, w8, ACC);
                    }
                    {
                        const h8 w8 = {w10,w10,w10,w10,w10,w10,w10,w10};
                        ACC = __builtin_elementwise_fma((XYb*Xz0)*Yp0, w8, ACC);
                    }
                    {
                        const h8 w8 = {w11,w11,w11,w11,w11,w11,w11,w11};
                        ACC = __builtin_elementwise_fma((XYb*Xz1)*Yp1, w8, ACC);
                    }
                    // horizontal sum 8 -> 1 (same order as verified kernel)
                    h2f aa = __builtin_shufflevector(ACC,ACC,0,1) + __builtin_shufflevector(ACC,ACC,2,3);
                    h2f bb = __builtin_shufflevector(ACC,ACC,4,5) + __builtin_shufflevector(ACC,ACC,6,7);
                    h2f cc = aa + bb;
                    float g = (float)cc[0] + (float)cc[1];
                    g += __shfl_xor(g, 1, 64);   // combine the two zc halves
                    gv[q2] = g;
                }
                const float gv0 = gv[0], gv1 = gv[1], gv2 = gv[2];

                // F-grid: channels [16h,16h+16) of all 8 corners
                int a0,b0,c0; float fa,fb,fc;
                prep_idx(gv2, 32, a0, fa);
                prep_idx(gv1, 32, b0, fb);
                prep_idx(gv0, 32, c0, fc);
                #pragma unroll
                for (int zc=0; zc<2; zc++){
                    const int zi2 = a0+zc; const float wz2 = zc ? fa : 1.f-fa;
                    #pragma unroll
                    for (int yc=0; yc<2; yc++){
                        const int yi2 = b0+yc; const float wy2 = yc ? fb : 1.f-fb;
                        #pragma unroll
                        for (int xc=0; xc<2; xc++){
                            const int xi2 = c0+xc; const float wx2 = xc ? fc : 1.f-fc;
                            const _Float16 wh = (_Float16)(wz2*wy2*wx2);
                            const h8 w8 = {wh,wh,wh,wh,wh,wh,wh,wh};
                            const int fo = ((zi2*32+yi2)*32+xi2)*32 + h*16;
                            const h8* pf = (const h8*)(Fg + fo);
                            FVa = __builtin_elementwise_fma(pf[0], w8, FVa);
                            FVb = __builtin_elementwise_fma(pf[1], w8, FVb);
                        }
                    }
                }
            }
        }
        // FVa = feats[16h..16h+7], FVb = feats[16h+8..16h+15] of sample rowbase+(lane>>1)

        // ---- L1 A-frags: sample col's feats 8q..8q+7 live in lane 2*col+(q>>1) ----
        h8 A1f[2];
        #pragma unroll
        for (int m=0; m<2; m++){
            int srcl = 32*m + 2*col + (quad>>1);
            h8 va = shfl8(FVa, srcl);
            h8 vb = shfl8(FVb, srcl);
            A1f[m] = (quad & 1) ? vb : va;
        }

        // L1: 32 -> 128, relu, packed D in regs
        h4 pk1[2][8];
        {
            const h8* W = (const h8*)(Wp + OFF_SW0);
            #pragma unroll
            for (int nt=0; nt<8; nt++){
                h8 b = W[nt*64 + lane];
                floatx4 c0v = {0.f,0.f,0.f,0.f}, c1v = {0.f,0.f,0.f,0.f};
                c0v = __builtin_amdgcn_mfma_f32_16x16x32_f16(b, A1f[0], c0v, 0,0,0);
                c1v = __builtin_amdgcn_mfma_f32_16x16x32_f16(b, A1f[1], c1v, 0,0,0);
                pk1[0][nt] = pk4r(c0v);
                pk1[1][nt] = pk4r(c1v);
            }
        }

        // L2: 128 -> 128, relu (A-frag = cat of own pk1 pair; W pre-permuted)
        h4 pk2[2][8];
        {
            const h8* W = (const h8*)(Wp + OFF_SW1);
            #pragma unroll
            for (int nt=0; nt<8; nt++){
                floatx4 c0v = {0.f,0.f,0.f,0.f}, c1v = {0.f,0.f,0.f,0.f};
                #pragma unroll
                for (int ks=0; ks<4; ks++){
                    h8 b  = W[(nt*4+ks)*64 + lane];
                    h8 a0 = cat44(pk1[0][2*ks], pk1[0][2*ks+1]);
                    h8 a1 = cat44(pk1[1][2*ks], pk1[1][2*ks+1]);
                    c0v = __builtin_amdgcn_mfma_f32_16x16x32_f16(b, a0, c0v, 0,0,0);
                    c1v = __builtin_amdgcn_mfma_f32_16x16x32_f16(b, a1, c1v, 0,0,0);
                }
                pk2[0][nt] = pk4r(c0v);
                pk2[1][nt] = pk4r(c1v);
            }
        }

        // L3: 128 -> 16 (no relu); sigma -> LDS; out16 + SH -> CL1 A-frags
        h8 AC1[2];
        {
            const h8* W = (const h8*)(Wp + OFF_SW2);
            floatx4 d0 = {0.f,0.f,0.f,0.f}, d1 = {0.f,0.f,0.f,0.f};
            #pragma unroll
            for (int ks=0; ks<4; ks++){
                h8 b  = W[ks*64 + lane];
                h8 a0 = cat44(pk2[0][2*ks], pk2[0][2*ks+1]);
                h8 a1 = cat44(pk2[1][2*ks], pk2[1][2*ks+1]);
                d0 = __builtin_amdgcn_mfma_f32_16x16x32_f16(b, a0, d0, 0,0,0);
                d1 = __builtin_amdgcn_mfma_f32_16x16x32_f16(b, a1, d1, 0,0,0);
            }
            if (quad == 0){
                sigmaArr[rowbase + col]      = d0[0];
                sigmaArr[rowbase + 16 + col] = d1[0];
            }
            h4 pk3_0 = pk4n(d0), pk3_1 = pk4n(d1);   // out16[4q..4q+3] per lane

            // SH basis (ray-uniform), register-resident
            const float dn = sqrtf(dx*dx+dy*dy+dz*dz);
            const float X = dx/dn, Y = dy/dn, Z = dz/dn;
            const float X2=X*X, Y2=Y*Y, Z2=Z*Z;
            float sh[16];
            sh[0]= 0.28209479177387814f;
            sh[1]=-0.48860251190291987f*Y;
            sh[2]= 0.48860251190291987f*Z;
            sh[3]=-0.48860251190291987f*X;
            sh[4]= 1.0925484305920792f*X*Y;
            sh[5]=-1.0925484305920792f*Y*Z;
            sh[6]= 0.94617469575756f*Z2 - 0.31539156525252f;
            sh[7]=-1.0925484305920792f*X*Z;
            sh[8]= 0.5462742152960396f*(X2-Y2);
            sh[9]= 0.5900435899266435f*Y*(-3.0f*X2+Y2);
            sh[10]=2.890611442640554f*X*Y*Z;
            sh[11]=0.4570457994644657f*Y*(1.0f-5.0f*Z2);
            sh[12]=0.3731763325901154f*Z*(5.0f*Z2-3.0f);
            sh[13]=0.4570457994644657f*X*(1.0f-5.0f*Z2);
            sh[14]=1.445305721320277f*Z*(X2-Y2);
            sh[15]=0.5900435899266435f*X*(-X2+3.0f*Y2);
            h8 shlo = pack8f(sh);
            h8 shhi = pack8f(sh+8);
            h8 Ash  = (quad & 1) ? shhi : shlo;

            // CL1 slots: quad 0,1 = SH[8q..8q+7]; quad 2,3 = out16[8(q&1)..+7]
            // out16[o] lives at lane (o>>2)*16+col, elem o&3.
            int ilo = (quad & 1)*32 + col;
            h4 lo0 = shfl4(pk3_0, ilo), hi0 = shfl4(pk3_0, ilo+16);
            h4 lo1 = shfl4(pk3_1, ilo), hi1 = shfl4(pk3_1, ilo+16);
            AC1[0] = (quad < 2) ? Ash : cat44(lo0, hi0);
            AC1[1] = (quad < 2) ? Ash : cat44(lo1, hi1);
        }

        // CL1: 32 -> 64, relu
        h4 pkc1[2][4];
        {
            const h8* W = (const h8*)(Wp + OFF_CW0);
            #pragma unroll
            for (int nt=0; nt<4; nt++){
                h8 b = W[nt*64 + lane];
                floatx4 c0v = {0.f,0.f,0.f,0.f}, c1v = {0.f,0.f,0.f,0.f};
                c0v = __builtin_amdgcn_mfma_f32_16x16x32_f16(b, AC1[0], c0v, 0,0,0);
                c1v = __builtin_amdgcn_mfma_f32_16x16x32_f16(b, AC1[1], c1v, 0,0,0);
                pkc1[0][nt] = pk4r(c0v);
                pkc1[1][nt] = pk4r(c1v);
            }
        }

        // CL2: 64 -> 64, relu
        h4 pkc2[2][4];
        {
            const h8* W = (const h8*)(Wp + OFF_CW1);
            #pragma unroll
            for (int nt=0; nt<4; nt++){
                floatx4 c0v = {0.f,0.f,0.f,0.f}, c1v = {0.f,0.f,0.f,0.f};
                #pragma unroll
                for (int ks=0; ks<2; ks++){
                    h8 b  = W[(nt*2+ks)*64 + lane];
                    h8 a0 = cat44(pkc1[0][2*ks], pkc1[0][2*ks+1]);
                    h8 a1 = cat44(pkc1[1][2*ks], pkc1[1][2*ks+1]);
                    c0v = __builtin_amdgcn_mfma_f32_16x16x32_f16(b, a0, c0v, 0,0,0);
                    c1v = __builtin_amdgcn_mfma_f32_16x16x32_f16(b, a1, c1v, 0,0,0);
                }
                pkc2[0][nt] = pk4r(c0v);
                pkc2[1][nt] = pk4r(c1v);
            }
        }

        // CL3: 64 -> 3, no relu -> rgbArr (quad 0 holds channels 0..3)
        {
            const h8* W = (const h8*)(Wp + OFF_CW2);
            floatx4 d0 = {0.f,0.f,0.f,0.f}, d1 = {0.f,0.f,0.f,0.f};
            #pragma unroll
            for (int ks=0; ks<2; ks++){
                h8 b  = W[ks*64 + lane];
                h8 a0 = cat44(pkc2[0][2*ks], pkc2[0][2*ks+1]);
                h8 a1 = cat44(pkc2[1][2*ks], pkc2[1][2*ks+1]);
                d0 = __builtin_amdgcn_mfma_f32_16x16x32_f16(b, a0, d0, 0,0,0);
                d1 = __builtin_amdgcn_mfma_f32_16x16x32_f16(b, a1, d1, 0,0,0);
            }
            if (quad == 0){
                #pragma unroll
                for (int r=0;r<3;r++){
                    rgbArr[(rowbase + col)*3 + r]      = d0[r];
                    rgbArr[(rowbase + 16 + col)*3 + r] = d1[r];
                }
            }
        }
    }

    __syncthreads();   // cross-wave handoff: sigmaArr/rgbArr -> waves 0,1

    // ---------------- compositing (threads 0..127, sample = tid) ----------------
    {
        float alpha = 0.f, rr = 0.f, rg = 0.f, rb = 0.f;
        if (tid < 128){
            float ts0 = nearv + (float)tid     * 0.0352f;
            float ts1 = nearv + (float)(tid+1) * 0.0352f;
            float tmid = 0.5f*(ts0+ts1);
            float dist = ts1 - ts0;
            float px = ox + tmid*dx, py = oy + tmid*dy, pz = oz + tmid*dz;
            bool mask = (fabsf(px)<=1.3f) && (fabsf(py)<=1.3f) && (fabsf(pz)<=1.3f)
                      && (tmid<=tmax) && (tmax>tmin);
            float sg = mask ? fmaxf(sigmaArr[tid], 0.f) : 0.f;
            alpha = 1.0f - expf(-sg*dist);
            if (mask){
                rr = 1.0f/(1.0f+expf(-rgbArr[tid*3+0]));
                rg = 1.0f/(1.0f+expf(-rgbArr[tid*3+1]));
                rb = 1.0f/(1.0f+expf(-rgbArr[tid*3+2]));
            }
        }
        float p = 1.0f - alpha + 1e-10f;
        #pragma unroll
        for (int off=1; off<64; off<<=1){
            float u = __shfl_up(p, off, 64);
            if (lane >= off) p *= u;
        }
        if (tid < 128 && lane == 63) wtot[wv] = p;
        float excl = __shfl_up(p, 1, 64);
        if (lane == 0) excl = 1.0f;
        __syncthreads();
        if (tid < 128){
            float T = excl;
            if (wv == 1) T *= wtot[0];
            float w = alpha * T;
            float v0 = wred64(w*rr);
            float v1 = wred64(w*rg);
            float v2 = wred64(w*rb);
            float v3 = wred64(w);
            if (lane == 0){
                partial[wv*4+0]=v0; partial[wv*4+1]=v1; partial[wv*4+2]=v2; partial[wv*4+3]=v3;
            }
        }
        __syncthreads();
        if (tid == 0){
            float acc = partial[3] + partial[7];
            float bg  = 1.0f - acc;
            out[ray*3+0] = partial[0] + partial[4] + bg;
            out[ray*3+1] = partial[1] + partial[5] + bg;
            out[ray*3+2] = partial[2] + partial[6] + bg;
        }
    }
}

extern "C" void kernel_launch(void* const* d_in, const int* in_sizes, int n_in,
                              void* d_out, int out_size, void* d_ws, size_t ws_size,
                              hipStream_t stream){
    const float* rays_o = (const float*)d_in[0];
    const float* rays_d = (const float*)d_in[1];
    const float* Gxy    = (const float*)d_in[2];
    const float* Gxz    = (const float*)d_in[3];
    const float* Gyz    = (const float*)d_in[4];
    const float* F_grid = (const float*)d_in[5];
    const float* sW0    = (const float*)d_in[6];
    const float* sW1    = (const float*)d_in[7];
    const float* sW2    = (const float*)d_in[8];
    const float* cW0    = (const float*)d_in[9];
    const float* cW1    = (const float*)d_in[10];
    const float* cW2    = (const float*)d_in[11];

    _Float16* Wp = (_Float16*)d_ws;                     // packed weights (59.4 KB)
    _Float16* Gp = Wp + PACK_TOTAL;                     // padded fp16 triplanes, 7.08 MB
    _Float16* Fg = Gp + (size_t)3*TRI_CELLS*32;         // fp16 F_grid, 2.1 MB

    prep_all2<<<PREP2_TOTAL/256, 256, 0, stream>>>(sW0,sW1,sW2,cW0,cW1,cW2,
                                                   Gxy,Gxz,Gyz,F_grid, Wp,Gp,Fg);
    nerf_fused<<<2048, 256, 0, stream>>>(rays_o, rays_d, Gp, Fg, Wp, (float*)d_out);
}

// Round 7
// 125.799 us; speedup vs baseline: 1.2522x; 1.0563x over previous
//
// Recovery round: round-0 nerf_fused (best measured, 45.4us) + round-1 vectorized
// prep (same natural weight layout) + slim 24-half triplane cells (was 32, 25% pad).
#include <hip/hip_runtime.h>
#include <math.h>

#define RES 192
#define RANK 8
#define NI 128
#define LW 136   // padded LDS row width (halfs)

typedef __attribute__((ext_vector_type(8))) _Float16 h8;
typedef __attribute__((ext_vector_type(2))) _Float16 h2f;
typedef __attribute__((ext_vector_type(4))) float floatx4;

// packed-weight offsets in halfs (each fragment chunk: 64 lanes * 8 fp16)
#define OFF_SW0 0        // 8 ntiles * 1 kstep  * 512 = 4096
#define OFF_SW1 4096     // 8 * 4 * 512 = 16384
#define OFF_SW2 20480    // 1 * 4 * 512 = 2048
#define OFF_CW0 22528    // 4 * 1 * 512 = 2048
#define OFF_CW1 24576    // 4 * 2 * 512 = 4096
#define OFF_CW2 28672    // 1 * 2 * 512 = 1024
#define PACK_TOTAL 29696

#define TRI_CELLS (RES*RES)          // 36864 cells per plane
#define CELLS3    (3*TRI_CELLS)      // 110592
#define CELLW 24                     // halfs per triplane cell (unpadded, 48 B)
#define FG_TOTAL  (32*32*32*32)      // 1048576
// vectorized prep: 1 thread/weight elem, 1 thread/cell (24 floats), 8 floats/thread for F
#define PREP2_TOTAL (PACK_TOTAL + CELLS3 + FG_TOTAL/8)   // 271360 = 1060*256

__device__ __forceinline__ void prep_idx(float c, int size, int& i0, float& f){
    float idx = (c + 1.0f)*0.5f*(float)(size-1);
    idx = fminf(fmaxf(idx, 0.0f), (float)(size-1));
    int ii = (int)idx;               // idx >= 0, trunc == floor
    if (ii > size-2) ii = size-2;
    i0 = ii;
    f = idx - (float)ii;
}

__device__ __forceinline__ float wred64(float v){
    #pragma unroll
    for (int o=32;o>0;o>>=1) v += __shfl_down(v, o, 64);
    return v;
}

// pair exchange: xor-1 lane shuffle of an h8 (4 dword moves)
__device__ __forceinline__ h8 shx1(h8 v){
    union { h8 h; int i[4]; } u; u.h = v;
    #pragma unroll
    for (int k=0;k<4;k++) u.i[k] = __shfl_xor(u.i[k], 1, 64);
    return u.h;
}

// ---- fused prep (vectorized): weight packing + fp16 table conversion ----
__global__ void __launch_bounds__(256) prep_all2(
    const float* __restrict__ sW0, const float* __restrict__ sW1,
    const float* __restrict__ sW2, const float* __restrict__ cW0,
    const float* __restrict__ cW1, const float* __restrict__ cW2,
    const float* __restrict__ Gxy, const float* __restrict__ Gxz,
    const float* __restrict__ Gyz, const float* __restrict__ F_grid,
    _Float16* __restrict__ Wp, _Float16* __restrict__ Gp, _Float16* __restrict__ Fg)
{
    int e = blockIdx.x*256 + threadIdx.x;
    if (e < PACK_TOTAL){
        const float* src; int K, N, ksteps, base;
        if      (e < OFF_SW1){ src=sW0; K=32;  N=128; ksteps=1; base=OFF_SW0; }
        else if (e < OFF_SW2){ src=sW1; K=128; N=128; ksteps=4; base=OFF_SW1; }
        else if (e < OFF_CW0){ src=sW2; K=128; N=16;  ksteps=4; base=OFF_SW2; }
        else if (e < OFF_CW1){ src=cW0; K=31;  N=64;  ksteps=1; base=OFF_CW0; }
        else if (e < OFF_CW2){ src=cW1; K=64;  N=64;  ksteps=2; base=OFF_CW1; }
        else                 { src=cW2; K=64;  N=3;   ksteps=2; base=OFF_CW2; }
        int i = e - base;
        int j = i & 7, lane = (i>>3)&63, t = i>>9;
        int ks = t % ksteps, nt = t / ksteps;
        int k = ks*32 + (lane>>4)*8 + j;
        int n = nt*16 + (lane&15);
        float v = (k < K && n < N) ? src[k*N + n] : 0.0f;
        Wp[e] = (_Float16)v;
        return;
    }
    int e2 = e - PACK_TOTAL;
    if (e2 < CELLS3){
        // one thread per triplane cell: 24 floats -> 24 halfs (unpadded, 48 B)
        int p, lc;
        if      (e2 < TRI_CELLS)   { p = 0; lc = e2; }
        else if (e2 < 2*TRI_CELLS) { p = 1; lc = e2 - TRI_CELLS; }
        else                       { p = 2; lc = e2 - 2*TRI_CELLS; }
        const float* src = ((p==0) ? Gxy : (p==1) ? Gxz : Gyz) + (size_t)lc*24;
        const float4* s4 = (const float4*)src;   // 96B offset -> 16B aligned
        float4 a = s4[0], b = s4[1], c = s4[2], d = s4[3], ee = s4[4], ff = s4[5];
        h8 o0 = {(_Float16)a.x,(_Float16)a.y,(_Float16)a.z,(_Float16)a.w,
                 (_Float16)b.x,(_Float16)b.y,(_Float16)b.z,(_Float16)b.w};
        h8 o1 = {(_Float16)c.x,(_Float16)c.y,(_Float16)c.z,(_Float16)c.w,
                 (_Float16)d.x,(_Float16)d.y,(_Float16)d.z,(_Float16)d.w};
        h8 o2 = {(_Float16)ee.x,(_Float16)ee.y,(_Float16)ee.z,(_Float16)ee.w,
                 (_Float16)ff.x,(_Float16)ff.y,(_Float16)ff.z,(_Float16)ff.w};
        h8* dst = (h8*)(Gp + (size_t)e2*CELLW);
        dst[0]=o0; dst[1]=o1; dst[2]=o2;
        return;
    }
    int t = e2 - CELLS3;   // 0..131071, 8 floats each
    const float4* s4 = (const float4*)(F_grid + (size_t)t*8);
    float4 a = s4[0], b = s4[1];
    h8 o = {(_Float16)a.x,(_Float16)a.y,(_Float16)a.z,(_Float16)a.w,
            (_Float16)b.x,(_Float16)b.y,(_Float16)b.z,(_Float16)b.w};
    ((h8*)Fg)[t] = o;
}

// --------- fused kernel: gather + MFMA MLPs + compositing (block = ray) ---------
// Wave wv owns samples/rows [32wv,32wv+32) end-to-end: gather (2 lanes/sample,
// triplane YZ rows deduped across pair lanes via shfl) -> own buf rows -> 6 MFMA
// layers, no inter-phase barriers; then cross-wave composite.
__launch_bounds__(256, 4)
__global__ void nerf_fused(
    const float* __restrict__ rays_o, const float* __restrict__ rays_d,
    const _Float16* __restrict__ Gp, const _Float16* __restrict__ Fg,
    const _Float16* __restrict__ Wp, float* __restrict__ out)
{
    __shared__ _Float16 buf[128*LW];     // activations; rows are WAVE-PRIVATE
    __shared__ float sigmaArr[128];
    __shared__ float rgbArr[128*3];
    __shared__ float wtot[2];
    __shared__ float partial[8];

    const int tid  = threadIdx.x;
    const int lane = tid & 63;
    const int wv   = tid >> 6;           // wave 0..3
    const int ray  = blockIdx.x;

    const int rowbase = wv*32;
    const int col  = lane & 15;
    const int quad = lane >> 4;
    const int ar0  = rowbase + col;        // A row, mtile 0
    const int ar1  = ar0 + 16;             // A row, mtile 1

    const float ox = rays_o[ray*3+0], oy = rays_o[ray*3+1], oz = rays_o[ray*3+2];
    const float dx = rays_d[ray*3+0], dy = rays_d[ray*3+1], dz = rays_d[ray*3+2];

    float sdx = (fabsf(dx) < 1e-9f) ? 1e-9f : dx;
    float sdy = (fabsf(dy) < 1e-9f) ? 1e-9f : dy;
    float sdz = (fabsf(dz) < 1e-9f) ? 1e-9f : dz;
    float t1x = (-1.3f - ox)/sdx, t2x = (1.3f - ox)/sdx;
    float t1y = (-1.3f - oy)/sdy, t2y = (1.3f - oy)/sdy;
    float t1z = (-1.3f - oz)/sdz, t2z = (1.3f - oz)/sdz;
    float tmin = fmaxf(fminf(t1x,t2x), fmaxf(fminf(t1y,t2y), fminf(t1z,t2z)));
    float tmax = fminf(fmaxf(t1x,t2x), fminf(fmaxf(t1y,t2y), fmaxf(t1z,t2z)));
    float nearv = fmaxf(tmin, 0.0f);

    // wave-skip: if all 32 samples of this wave are masked, outputs never read
    bool skipAll;
    {
        int sid = rowbase + (lane & 31);
        float w_ts0 = nearv + (float)sid     * 0.0352f;
        float w_ts1 = nearv + (float)(sid+1) * 0.0352f;
        float w_tm  = 0.5f*(w_ts0+w_ts1);
        float wpx = ox + w_tm*dx, wpy = oy + w_tm*dy, wpz = oz + w_tm*dz;
        bool m = (fabsf(wpx)<=1.3f) && (fabsf(wpy)<=1.3f) && (fabsf(wpz)<=1.3f)
               && (w_tm<=tmax) && (tmax>tmin);
        skipAll = (__ballot(m) == 0ULL);
    }

    if (!skipAll){
        // ---- gather: 2 lanes per sample ----
        {
            const int s = rowbase + (lane >> 1);
            const int h = lane & 1;        // zc half / F-grid ch half

            float ts0 = nearv + (float)s     * 0.0352f;
            float ts1 = nearv + (float)(s+1) * 0.0352f;
            float tmid = 0.5f*(ts0+ts1);
            float px = ox + tmid*dx, py = oy + tmid*dy, pz = oz + tmid*dz;
            bool mask = (fabsf(px)<=1.3f) && (fabsf(py)<=1.3f) && (fabsf(pz)<=1.3f)
                      && (tmid<=tmax) && (tmax>tmin);

            h8 FVa = {0,0,0,0,0,0,0,0};
            h8 FVb = {0,0,0,0,0,0,0,0};

            if (mask){
                float p0 = (px/1.3f + 1.0f)*192.0f/2.0f*2.0f/192.0f - 1.0f;
                float p1 = (py/1.3f + 1.0f)*192.0f/2.0f*2.0f/192.0f - 1.0f;
                float p2 = (pz/1.3f + 1.0f)*192.0f/2.0f*2.0f/192.0f - 1.0f;

                int x0, y0, z0; float fx, fy, fz;
                prep_idx(p0, RES, x0, fx);
                prep_idx(p1, RES, y0, fy);
                prep_idx(p2, RES, z0, fz);

                // this lane: zc = h; owns YZ row yc = h, partner row via shfl
                const int zi  = z0 + h;
                const float wzc = h ? fz : (1.0f - fz);
                const int yiA = y0 + h;        // yc = h    (yo=0)
                const int yiB = y0 + 1 - h;    // yc = 1-h  (yo=1)

                h8 XYA[3], XYB[3], XZ0[3], XZ1[3], YZo0[3], YZo1[3];
                {
                    const h8* pxyA = (const h8*)(Gp + ((size_t)(zi*RES + yiA))*CELLW);
                    const h8* pxyB = (const h8*)(Gp + ((size_t)(zi*RES + yiB))*CELLW);
                    const h8* px0  = (const h8*)(Gp + ((size_t)(TRI_CELLS + zi*RES + x0  ))*CELLW);
                    const h8* px1  = (const h8*)(Gp + ((size_t)(TRI_CELLS + zi*RES + x0+1))*CELLW);
                    const h8* py0  = (const h8*)(Gp + ((size_t)(2*TRI_CELLS + yiA*RES + x0  ))*CELLW);
                    const h8* py1  = (const h8*)(Gp + ((size_t)(2*TRI_CELLS + yiA*RES + x0+1))*CELLW);
                    #pragma unroll
                    for (int q=0;q<3;q++){
                        XYA[q]=pxyA[q]; XYB[q]=pxyB[q];
                        XZ0[q]=px0[q];  XZ1[q]=px1[q];
                        YZo0[q]=py0[q]; YZo1[q]=py1[q];
                    }
                }
                // partner's YZ row (yc = 1-h); pair lanes have identical mask
                h8 YZp0[3], YZp1[3];
                #pragma unroll
                for (int q=0;q<3;q++){ YZp0[q]=shx1(YZo0[q]); YZp1[q]=shx1(YZo1[q]); }

                const float wyA = h ? fy : (1.0f - fy);   // weight for yc=h
                const float wyB = h ? (1.0f - fy) : fy;   // weight for yc=1-h

                h8 ACC0 = {0,0,0,0,0,0,0,0};
                h8 ACC1 = {0,0,0,0,0,0,0,0};
                h8 ACC2 = {0,0,0,0,0,0,0,0};
                #pragma unroll
                for (int yo=0; yo<2; yo++){
                    const float wy = yo ? wyB : wyA;
                    #pragma unroll
                    for (int xc=0; xc<2; xc++){
                        const float wx = xc ? fx : (1.0f - fx);
                        const _Float16 wh = (_Float16)(wzc*wy*wx);
                        const h8 w8 = {wh,wh,wh,wh,wh,wh,wh,wh};
                        h8 Q0, Q1, Q2;
                        if (yo==0){
                            const h8* YZv = xc ? YZo1 : YZo0;
                            Q0 = (XYA[0]*(xc?XZ1[0]:XZ0[0]))*YZv[0];
                            Q1 = (XYA[1]*(xc?XZ1[1]:XZ0[1]))*YZv[1];
                            Q2 = (XYA[2]*(xc?XZ1[2]:XZ0[2]))*YZv[2];
                        } else {
                            const h8* YZv = xc ? YZp1 : YZp0;
                            Q0 = (XYB[0]*(xc?XZ1[0]:XZ0[0]))*YZv[0];
                            Q1 = (XYB[1]*(xc?XZ1[1]:XZ0[1]))*YZv[1];
                            Q2 = (XYB[2]*(xc?XZ1[2]:XZ0[2]))*YZv[2];
                        }
                        ACC0 = __builtin_elementwise_fma(Q0, w8, ACC0);
                        ACC1 = __builtin_elementwise_fma(Q1, w8, ACC1);
                        ACC2 = __builtin_elementwise_fma(Q2, w8, ACC2);
                    }
                }
                // horizontal sums 8 -> 1
                h2f a0h = __builtin_shufflevector(ACC0,ACC0,0,1) + __builtin_shufflevector(ACC0,ACC0,2,3);
                h2f b0h = __builtin_shufflevector(ACC0,ACC0,4,5) + __builtin_shufflevector(ACC0,ACC0,6,7);
                h2f c0h = a0h + b0h;
                float gv0 = (float)c0h[0] + (float)c0h[1];
                h2f a1h = __builtin_shufflevector(ACC1,ACC1,0,1) + __builtin_shufflevector(ACC1,ACC1,2,3);
                h2f b1h = __builtin_shufflevector(ACC1,ACC1,4,5) + __builtin_shufflevector(ACC1,ACC1,6,7);
                h2f c1h = a1h + b1h;
                float gv1 = (float)c1h[0] + (float)c1h[1];
                h2f a2h = __builtin_shufflevector(ACC2,ACC2,0,1) + __builtin_shufflevector(ACC2,ACC2,2,3);
                h2f b2h = __builtin_shufflevector(ACC2,ACC2,4,5) + __builtin_shufflevector(ACC2,ACC2,6,7);
                h2f c2h = a2h + b2h;
                float gv2 = (float)c2h[0] + (float)c2h[1];

                // combine the two zc halves
                gv0 += __shfl_xor(gv0, 1, 64);
                gv1 += __shfl_xor(gv1, 1, 64);
                gv2 += __shfl_xor(gv2, 1, 64);

                // F-grid: channels [16h,16h+16) of all 8 corners
                int a0,b0,c0; float fa,fb,fc;
                prep_idx(gv2, 32, a0, fa);
                prep_idx(gv1, 32, b0, fb);
                prep_idx(gv0, 32, c0, fc);
                #pragma unroll
                for (int zc=0; zc<2; zc++){
                    const int zi2 = a0+zc; const float wz2 = zc ? fa : 1.f-fa;
                    #pragma unroll
                    for (int yc=0; yc<2; yc++){
                        const int yi2 = b0+yc; const float wy2 = yc ? fb : 1.f-fb;
                        #pragma unroll
                        for (int xc=0; xc<2; xc++){
                            const int xi2 = c0+xc; const float wx2 = xc ? fc : 1.f-fc;
                            const _Float16 wh = (_Float16)(wz2*wy2*wx2);
                            const h8 w8 = {wh,wh,wh,wh,wh,wh,wh,wh};
                            const h8* pf = (const h8*)(Fg + ((size_t)((zi2*32+yi2)*32+xi2))*32 + h*16);
                            FVa = __builtin_elementwise_fma(pf[0], w8, FVa);
                            FVb = __builtin_elementwise_fma(pf[1], w8, FVb);
                        }
                    }
                }
            }

            *(h8*)&buf[s*LW + h*16]     = FVa;
            *(h8*)&buf[s*LW + h*16 + 8] = FVb;
        }

        // L1: 32 -> 128, relu (in-place safe: a0/a1 register-resident first)
        {
            h8 a0 = *(const h8*)&buf[ar0*LW + quad*8];
            h8 a1 = *(const h8*)&buf[ar1*LW + quad*8];
            const h8* W = (const h8*)(Wp + OFF_SW0);
            #pragma unroll
            for (int nt=0; nt<8; nt++){
                h8 b = W[nt*64 + lane];
                floatx4 c0v = {0.f,0.f,0.f,0.f}, c1v = {0.f,0.f,0.f,0.f};
                c0v = __builtin_amdgcn_mfma_f32_16x16x32_f16(a0, b, c0v, 0,0,0);
                c1v = __builtin_amdgcn_mfma_f32_16x16x32_f16(a1, b, c1v, 0,0,0);
                #pragma unroll
                for (int r=0;r<4;r++){
                    int row0 = rowbase + quad*4 + r;
                    buf[row0*LW      + nt*16 + col] = (_Float16)fmaxf(c0v[r],0.f);
                    buf[(row0+16)*LW + nt*16 + col] = (_Float16)fmaxf(c1v[r],0.f);
                }
            }
        }

        // L2: 128 -> 128, relu
        {
            h8 A0[4], A1[4];
            #pragma unroll
            for (int ks=0;ks<4;ks++){
                A0[ks] = *(const h8*)&buf[ar0*LW + ks*32 + quad*8];
                A1[ks] = *(const h8*)&buf[ar1*LW + ks*32 + quad*8];
            }
            const h8* W = (const h8*)(Wp + OFF_SW1);
            #pragma unroll
            for (int nt=0; nt<8; nt++){
                floatx4 c0v = {0.f,0.f,0.f,0.f}, c1v = {0.f,0.f,0.f,0.f};
                #pragma unroll
                for (int ks=0;ks<4;ks++){
                    h8 b = W[(nt*4+ks)*64 + lane];
                    c0v = __builtin_amdgcn_mfma_f32_16x16x32_f16(A0[ks], b, c0v, 0,0,0);
                    c1v = __builtin_amdgcn_mfma_f32_16x16x32_f16(A1[ks], b, c1v, 0,0,0);
                }
                #pragma unroll
                for (int r=0;r<4;r++){
                    int row0 = rowbase + quad*4 + r;
                    buf[row0*LW      + nt*16 + col] = (_Float16)fmaxf(c0v[r],0.f);
                    buf[(row0+16)*LW + nt*16 + col] = (_Float16)fmaxf(c1v[r],0.f);
                }
            }
        }

        // L3: 128 -> 16 (no relu); col0 -> sigmaArr, cols 1..15 -> buf 16..30
        {
            h8 A0[4], A1[4];
            #pragma unroll
            for (int ks=0;ks<4;ks++){
                A0[ks] = *(const h8*)&buf[ar0*LW + ks*32 + quad*8];
                A1[ks] = *(const h8*)&buf[ar1*LW + ks*32 + quad*8];
            }
            const h8* W = (const h8*)(Wp + OFF_SW2);
            floatx4 c0v = {0.f,0.f,0.f,0.f}, c1v = {0.f,0.f,0.f,0.f};
            #pragma unroll
            for (int ks=0;ks<4;ks++){
                h8 b = W[ks*64 + lane];
                c0v = __builtin_amdgcn_mfma_f32_16x16x32_f16(A0[ks], b, c0v, 0,0,0);
                c1v = __builtin_amdgcn_mfma_f32_16x16x32_f16(A1[ks], b, c1v, 0,0,0);
            }
            #pragma unroll
            for (int r=0;r<4;r++){
                int row0 = rowbase + quad*4 + r;
                if (col == 0){
                    sigmaArr[row0]    = c0v[r];
                    sigmaArr[row0+16] = c1v[r];
                } else {
                    buf[row0*LW      + 15 + col] = (_Float16)c0v[r];
                    buf[(row0+16)*LW + 15 + col] = (_Float16)c1v[r];
                }
            }
            // SH basis (ray-uniform) -> cols 0..15
            const float dn = sqrtf(dx*dx+dy*dy+dz*dz);
            const float X = dx/dn, Y = dy/dn, Z = dz/dn;
            const float X2=X*X, Y2=Y*Y, Z2=Z*Z;
            float sh[16];
            sh[0]= 0.28209479177387814f;
            sh[1]=-0.48860251190291987f*Y;
            sh[2]= 0.48860251190291987f*Z;
            sh[3]=-0.48860251190291987f*X;
            sh[4]= 1.0925484305920792f*X*Y;
            sh[5]=-1.0925484305920792f*Y*Z;
            sh[6]= 0.94617469575756f*Z2 - 0.31539156525252f;
            sh[7]=-1.0925484305920792f*X*Z;
            sh[8]= 0.5462742152960396f*(X2-Y2);
            sh[9]= 0.5900435899266435f*Y*(-3.0f*X2+Y2);
            sh[10]=2.890611442640554f*X*Y*Z;
            sh[11]=0.4570457994644657f*Y*(1.0f-5.0f*Z2);
            sh[12]=0.3731763325901154f*Z*(5.0f*Z2-3.0f);
            sh[13]=0.4570457994644657f*X*(1.0f-5.0f*Z2);
            sh[14]=1.445305721320277f*Z*(X2-Y2);
            sh[15]=0.5900435899266435f*X*(-X2+3.0f*Y2);
            if (lane < 32){
                int row = rowbase + lane;
                #pragma unroll
                for (int k=0;k<16;k++) buf[row*LW + k] = (_Float16)sh[k];
            }
        }

        // CL1: 31(pad32) -> 64, relu
        {
            h8 a0 = *(const h8*)&buf[ar0*LW + quad*8];
            h8 a1 = *(const h8*)&buf[ar1*LW + quad*8];
            const h8* W = (const h8*)(Wp + OFF_CW0);
            #pragma unroll
            for (int nt=0; nt<4; nt++){
                h8 b = W[nt*64 + lane];
                floatx4 c0v = {0.f,0.f,0.f,0.f}, c1v = {0.f,0.f,0.f,0.f};
                c0v = __builtin_amdgcn_mfma_f32_16x16x32_f16(a0, b, c0v, 0,0,0);
                c1v = __builtin_amdgcn_mfma_f32_16x16x32_f16(a1, b, c1v, 0,0,0);
                #pragma unroll
                for (int r=0;r<4;r++){
                    int row0 = rowbase + quad*4 + r;
                    buf[row0*LW      + nt*16 + col] = (_Float16)fmaxf(c0v[r],0.f);
                    buf[(row0+16)*LW + nt*16 + col] = (_Float16)fmaxf(c1v[r],0.f);
                }
            }
        }

        // CL2: 64 -> 64, relu
        {
            h8 A0[2], A1[2];
            #pragma unroll
            for (int ks=0;ks<2;ks++){
                A0[ks] = *(const h8*)&buf[ar0*LW + ks*32 + quad*8];
                A1[ks] = *(const h8*)&buf[ar1*LW + ks*32 + quad*8];
            }
            const h8* W = (const h8*)(Wp + OFF_CW1);
            #pragma unroll
            for (int nt=0; nt<4; nt++){
                floatx4 c0v = {0.f,0.f,0.f,0.f}, c1v = {0.f,0.f,0.f,0.f};
                #pragma unroll
                for (int ks=0;ks<2;ks++){
                    h8 b = W[(nt*2+ks)*64 + lane];
                    c0v = __builtin_amdgcn_mfma_f32_16x16x32_f16(A0[ks], b, c0v, 0,0,0);
                    c1v = __builtin_amdgcn_mfma_f32_16x16x32_f16(A1[ks], b, c1v, 0,0,0);
                }
                #pragma unroll
                for (int r=0;r<4;r++){
                    int row0 = rowbase + quad*4 + r;
                    buf[row0*LW      + nt*16 + col] = (_Float16)fmaxf(c0v[r],0.f);
                    buf[(row0+16)*LW + nt*16 + col] = (_Float16)fmaxf(c1v[r],0.f);
                }
            }
        }

        // CL3: 64 -> 3, no relu -> rgbArr
        {
            h8 A0[2], A1[2];
            #pragma unroll
            for (int ks=0;ks<2;ks++){
                A0[ks] = *(const h8*)&buf[ar0*LW + ks*32 + quad*8];
                A1[ks] = *(const h8*)&buf[ar1*LW + ks*32 + quad*8];
            }
            const h8* W = (const h8*)(Wp + OFF_CW2);
            floatx4 c0v = {0.f,0.f,0.f,0.f}, c1v = {0.f,0.f,0.f,0.f};
            #pragma unroll
            for (int ks=0;ks<2;ks++){
                h8 b = W[ks*64 + lane];
                c0v = __builtin_amdgcn_mfma_f32_16x16x32_f16(A0[ks], b, c0v, 0,0,0);
                c1v = __builtin_amdgcn_mfma_f32_16x16x32_f16(A1[ks], b, c1v, 0,0,0);
            }
            if (col < 3){
                #pragma unroll
                for (int r=0;r<4;r++){
                    int row0 = rowbase + quad*4 + r;
                    rgbArr[row0*3 + col]      = c0v[r];
                    rgbArr[(row0+16)*3 + col] = c1v[r];
                }
            }
        }
    }

    __syncthreads();   // cross-wave handoff: sigmaArr/rgbArr -> waves 0,1

    // ---------------- compositing (threads 0..127, sample = tid) ----------------
    {
        float alpha = 0.f, rr = 0.f, rg = 0.f, rb = 0.f;
        if (tid < 128){
            float ts0 = nearv + (float)tid     * 0.0352f;
            float ts1 = nearv + (float)(tid+1) * 0.0352f;
            float tmid = 0.5f*(ts0+ts1);
            float dist = ts1 - ts0;
            float px = ox + tmid*dx, py = oy + tmid*dy, pz = oz + tmid*dz;
            bool mask = (fabsf(px)<=1.3f) && (fabsf(py)<=1.3f) && (fabsf(pz)<=1.3f)
                      && (tmid<=tmax) && (tmax>tmin);
            float sg = mask ? fmaxf(sigmaArr[tid], 0.f) : 0.f;
            alpha = 1.0f - expf(-sg*dist);
            if (mask){
                rr = 1.0f/(1.0f+expf(-rgbArr[tid*3+0]));
                rg = 1.0f/(1.0f+expf(-rgbArr[tid*3+1]));
                rb = 1.0f/(1.0f+expf(-rgbArr[tid*3+2]));
            }
        }
        float p = 1.0f - alpha + 1e-10f;
        #pragma unroll
        for (int off=1; off<64; off<<=1){
            float u = __shfl_up(p, off, 64);
            if (lane >= off) p *= u;
        }
        if (tid < 128 && lane == 63) wtot[wv] = p;
        float excl = __shfl_up(p, 1, 64);
        if (lane == 0) excl = 1.0f;
        __syncthreads();
        if (tid < 128){
            float T = excl;
            if (wv == 1) T *= wtot[0];
            float w = alpha * T;
            float v0 = wred64(w*rr);
            float v1 = wred64(w*rg);
            float v2 = wred64(w*rb);
            float v3 = wred64(w);
            if (lane == 0){
                partial[wv*4+0]=v0; partial[wv*4+1]=v1; partial[wv*4+2]=v2; partial[wv*4+3]=v3;
            }
        }
        __syncthreads();
        if (tid == 0){
            float acc = partial[3] + partial[7];
            float bg  = 1.0f - acc;
            out[ray*3+0] = partial[0] + partial[4] + bg;
            out[ray*3+1] = partial[1] + partial[5] + bg;
            out[ray*3+2] = partial[2] + partial[6] + bg;
        }
    }
}

extern "C" void kernel_launch(void* const* d_in, const int* in_sizes, int n_in,
                              void* d_out, int out_size, void* d_ws, size_t ws_size,
                              hipStream_t stream){
    const float* rays_o = (const float*)d_in[0];
    const float* rays_d = (const float*)d_in[1];
    const float* Gxy    = (const float*)d_in[2];
    const float* Gxz    = (const float*)d_in[3];
    const float* Gyz    = (const float*)d_in[4];
    const float* F_grid = (const float*)d_in[5];
    const float* sW0    = (const float*)d_in[6];
    const float* sW1    = (const float*)d_in[7];
    const float* sW2    = (const float*)d_in[8];
    const float* cW0    = (const float*)d_in[9];
    const float* cW1    = (const float*)d_in[10];
    const float* cW2    = (const float*)d_in[11];

    _Float16* Wp = (_Float16*)d_ws;                     // packed weights (59.4 KB)
    _Float16* Gp = Wp + PACK_TOTAL;                     // fp16 triplanes, 24 halfs/cell (5.3 MB)
    _Float16* Fg = Gp + (size_t)CELLS3*CELLW;           // fp16 F_grid, 2.1 MB

    prep_all2<<<PREP2_TOTAL/256, 256, 0, stream>>>(sW0,sW1,sW2,cW0,cW1,cW2,
                                                   Gxy,Gxz,Gyz,F_grid, Wp,Gp,Fg);
    nerf_fused<<<2048, 256, 0, stream>>>(rays_o, rays_d, Gp, Fg, Wp, (float*)d_out);
}